// Round 2
// 795.452 us; speedup vs baseline: 1.0110x; 1.0110x over previous
//
#include <hip/hip_runtime.h>

// B=2,H=16,S=2048,D=64 fp32; temp=8; outputs: O [B,H,S,D] then attn [B,H,S,S].
// S^T = K*Q^T per MFMA tile so each lane owns 4 consecutive keys of one query.
// v3: fixed tr-read granule model: 128B-aligned granules [4 keys][16 d], lane
// base = quad*512 + ln15*8, offsets m*4096+h*2048+c*128. PV A-frag = lane-local
// P (keys permuted identically on A and B). cvt_pk via __bf16 casts; Q
// pre-scaled by 1/temp (exact pow2); nontemporal attn stores.

#define S 2048
#define D 64
#define HH 16
#define BB 2
#define LDK 72  // bf16 elems per LDS row for K tile (144B; conflict-benign)

typedef __attribute__((ext_vector_type(8))) short short8;
typedef __attribute__((ext_vector_type(4))) float f32x4;
typedef __attribute__((ext_vector_type(2))) unsigned int u32x2;

__device__ __forceinline__ unsigned int packbf2(float a, float b) {
  union { __bf16 h[2]; unsigned int u; } r;
  r.h[0] = (__bf16)a;  // RNE fptrunc -> v_cvt_pk_bf16_f32 on gfx950
  r.h[1] = (__bf16)b;
  return r.u;
}
__device__ __forceinline__ short8 cvt8(float4 a, float4 b) {
  union { unsigned int u[4]; short8 s; } r;
  r.u[0] = packbf2(a.x, a.y); r.u[1] = packbf2(a.z, a.w);
  r.u[2] = packbf2(b.x, b.y); r.u[3] = packbf2(b.z, b.w);
  return r.s;
}
__device__ __forceinline__ float4 qscale(float4 v) {
  return make_float4(v.x * 0.125f, v.y * 0.125f, v.z * 0.125f, v.w * 0.125f);
}

// hardware transpose read: granule = (addr & ~127); column = (addr & 127)/8;
// returns rows 0..3 (bytes granule + col*2 + {0,32,64,96})
#define TRRD(dst, addr, off) \
  asm volatile("ds_read_b64_tr_b16 %0, %1 offset:" #off : "=v"(dst) : "v"(addr))

// ---- pre-pass: pack mask ints -> 1 bit per element (u64 covers 64 keys) ----
__global__ __launch_bounds__(256) void pack_mask_kernel(
    const int* __restrict__ m, unsigned long long* __restrict__ bits) {
  int wid = blockIdx.x * 4 + (threadIdx.x >> 6);
  int lane = threadIdx.x & 63;
  int v = m[(size_t)wid * 64 + lane];
  unsigned long long b = __ballot(v != 0);
  if (lane == 0) bits[wid] = b;
}

__global__ __launch_bounds__(256) void attn_kernel(
    const float* __restrict__ Qg, const float* __restrict__ Kg,
    const float* __restrict__ Vg, const unsigned long long* __restrict__ Mb,
    float* __restrict__ Og, float* __restrict__ Ag) {
  __shared__ alignas(128) unsigned short Vt[64 * 64];  // 64 granules of 4x16
  __shared__ unsigned short Kt[64 * LDK];

  const int tid = threadIdx.x;
  const int w = tid >> 6;
  const int lane = tid & 63;
  const int ln15 = lane & 15;
  const int quad = lane >> 4;

  const int bh = blockIdx.x;  // bh fastest -> each XCD sees ~4 heads
  const int qtile = blockIdx.y;
  const int b = bh >> 4;
  const size_t qkvbase = (size_t)bh * S * D;
  const int q0 = qtile * 64;
  const int qrow = q0 + w * 16 + ln15;

  // Q fragments direct from global, pre-scaled by 1/temperature (exact pow2)
  const float4* qp = reinterpret_cast<const float4*>(Qg + qkvbase + (size_t)qrow * D);
  short8 aq0, aq1;
  {
    float4 a0 = qscale(qp[quad * 2]), a1 = qscale(qp[quad * 2 + 1]);
    float4 b0 = qscale(qp[8 + quad * 2]), b1 = qscale(qp[8 + quad * 2 + 1]);
    aq0 = cvt8(a0, a1);
    aq1 = cvt8(b0, b1);
  }

  const unsigned long long* mrow = Mb + ((size_t)b * S + qrow) * (S / 64);

  const int trow = tid >> 2;        // staging: key row
  const int tcol = (tid & 3) << 4;  // staging: d offset (16 floats per thread)

  // =============== PASS 1: per-query sum of exp(masked scores) ===============
  float lsum = 0.f;
  float4 kf0, kf1, kf2, kf3;
  {
    const float4* src = reinterpret_cast<const float4*>(Kg + qkvbase + (size_t)trow * D + tcol);
    kf0 = src[0]; kf1 = src[1]; kf2 = src[2]; kf3 = src[3];
  }
  unsigned long long mw = mrow[0];
  for (int t = 0; t < 32; ++t) {
    __syncthreads();
    *reinterpret_cast<short8*>(&Kt[trow * LDK + tcol]) = cvt8(kf0, kf1);
    *reinterpret_cast<short8*>(&Kt[trow * LDK + tcol + 8]) = cvt8(kf2, kf3);
    __syncthreads();
    if (t < 31) {
      const float4* src = reinterpret_cast<const float4*>(
          Kg + qkvbase + (size_t)((t + 1) * 64 + trow) * D + tcol);
      kf0 = src[0]; kf1 = src[1]; kf2 = src[2]; kf3 = src[3];
    }
    unsigned long long mwn = (t < 31) ? mrow[t + 1] : 0ULL;
#pragma unroll
    for (int kt = 0; kt < 4; ++kt) {
      short8 bk0 = *reinterpret_cast<const short8*>(&Kt[(kt * 16 + ln15) * LDK + (quad << 3)]);
      short8 bk1 = *reinterpret_cast<const short8*>(&Kt[(kt * 16 + ln15) * LDK + 32 + (quad << 3)]);
      f32x4 acc = {0.f, 0.f, 0.f, 0.f};
      acc = __builtin_amdgcn_mfma_f32_16x16x32_bf16(bk0, aq0, acc, 0, 0, 0);
      acc = __builtin_amdgcn_mfma_f32_16x16x32_bf16(bk1, aq1, acc, 0, 0, 0);
      unsigned int nib = (unsigned int)(mw >> (kt * 16 + quad * 4)) & 0xFu;
#pragma unroll
      for (int r = 0; r < 4; ++r) {
        float e = __expf(acc[r]);
        lsum += ((nib >> r) & 1u) ? e : 0.f;
      }
    }
    mw = mwn;
  }
  lsum += __shfl_xor(lsum, 16, 64);
  lsum += __shfl_xor(lsum, 32, 64);
  const float rinv = (lsum > 0.f) ? 1.f / lsum : 0.f;

  // =============== PASS 2: write attn (nt float4), O = P*V ===============
  float* arow = Ag + ((size_t)bh * S + qrow) * S;
  f32x4 oacc[4] = {{0.f, 0.f, 0.f, 0.f}, {0.f, 0.f, 0.f, 0.f},
                   {0.f, 0.f, 0.f, 0.f}, {0.f, 0.f, 0.f, 0.f}};

  // V granule layout: G = (key>>2)*4 + (d>>4), elem (key&3)*16 + (d&15).
  // tr-read lane addr: granule (m*8 + h*4 + quad)*4 + c, column ln15.
  const unsigned int vbase = (unsigned int)(unsigned long long)(const void*)&Vt[0];
  const unsigned int vb = vbase + (unsigned int)(quad * 512 + ln15 * 8);
  const int vwoff = ((trow >> 2) * 4 + (tid & 3)) * 64 + (trow & 3) * 16;

  float4 vf0, vf1, vf2, vf3;
  {
    const float4* src = reinterpret_cast<const float4*>(Kg + qkvbase + (size_t)trow * D + tcol);
    kf0 = src[0]; kf1 = src[1]; kf2 = src[2]; kf3 = src[3];
    const float4* vs = reinterpret_cast<const float4*>(Vg + qkvbase + (size_t)trow * D + tcol);
    vf0 = vs[0]; vf1 = vs[1]; vf2 = vs[2]; vf3 = vs[3];
  }
  mw = mrow[0];
  for (int t = 0; t < 32; ++t) {
    __syncthreads();
    *reinterpret_cast<short8*>(&Kt[trow * LDK + tcol]) = cvt8(kf0, kf1);
    *reinterpret_cast<short8*>(&Kt[trow * LDK + tcol + 8]) = cvt8(kf2, kf3);
    *reinterpret_cast<short8*>(&Vt[vwoff]) = cvt8(vf0, vf1);
    *reinterpret_cast<short8*>(&Vt[vwoff + 8]) = cvt8(vf2, vf3);
    __syncthreads();
    if (t < 31) {
      const float4* src = reinterpret_cast<const float4*>(
          Kg + qkvbase + (size_t)((t + 1) * 64 + trow) * D + tcol);
      kf0 = src[0]; kf1 = src[1]; kf2 = src[2]; kf3 = src[3];
      const float4* vs = reinterpret_cast<const float4*>(
          Vg + qkvbase + (size_t)((t + 1) * 64 + trow) * D + tcol);
      vf0 = vs[0]; vf1 = vs[1]; vf2 = vs[2]; vf3 = vs[3];
    }
    unsigned long long mwn = (t < 31) ? mrow[t + 1] : 0ULL;
    const int k0 = t * 64;
    unsigned int apu[8];
#pragma unroll
    for (int kt = 0; kt < 4; ++kt) {
      short8 bk0 = *reinterpret_cast<const short8*>(&Kt[(kt * 16 + ln15) * LDK + (quad << 3)]);
      short8 bk1 = *reinterpret_cast<const short8*>(&Kt[(kt * 16 + ln15) * LDK + 32 + (quad << 3)]);
      f32x4 acc = {0.f, 0.f, 0.f, 0.f};
      acc = __builtin_amdgcn_mfma_f32_16x16x32_bf16(bk0, aq0, acc, 0, 0, 0);
      acc = __builtin_amdgcn_mfma_f32_16x16x32_bf16(bk1, aq1, acc, 0, 0, 0);
      unsigned int nib = (unsigned int)(mw >> (kt * 16 + quad * 4)) & 0xFu;
      f32x4 p;
#pragma unroll
      for (int r = 0; r < 4; ++r) {
        float e = __expf(acc[r]) * rinv;
        p[r] = ((nib >> r) & 1u) ? e : 0.f;
      }
      __builtin_nontemporal_store(p, reinterpret_cast<f32x4*>(arow + k0 + kt * 16 + quad * 4));
      // lane owns P[query ln15][key kt*16 + quad*4 + r]; A-frag key order for
      // chunk m: j=0..3 -> m*32+quad*4+j (kt=2m), j=4..7 -> m*32+16+quad*4+(j-4)
      apu[kt * 2] = packbf2(p[0], p[1]);
      apu[kt * 2 + 1] = packbf2(p[2], p[3]);
    }
    // B-frags via tr-reads; granule (m*8 + h*4 + quad)*4 + c, column ln15.
    // offset = m*4096 + h*2048 + c*128 (relative to vb which folds quad*512)
    u32x2 x0, x1, x2, x3, x4, x5, x6, x7, x8, x9, x10, x11, x12, x13, x14, x15;
    TRRD(x0, vb, 0);     TRRD(x1, vb, 2048);
    TRRD(x2, vb, 128);   TRRD(x3, vb, 2176);
    TRRD(x4, vb, 256);   TRRD(x5, vb, 2304);
    TRRD(x6, vb, 384);   TRRD(x7, vb, 2432);
    TRRD(x8, vb, 4096);  TRRD(x9, vb, 6144);
    TRRD(x10, vb, 4224); TRRD(x11, vb, 6272);
    TRRD(x12, vb, 4352); TRRD(x13, vb, 6400);
    TRRD(x14, vb, 4480); TRRD(x15, vb, 6528);
    asm volatile("s_waitcnt lgkmcnt(0)" ::: "memory");
    __builtin_amdgcn_sched_barrier(0);  // rule-18: keep MFMAs below the wait
    union Frag { unsigned int u[4]; u32x2 d[2]; short8 s; };
    Frag ap0, ap1, bv;
    ap0.u[0] = apu[0]; ap0.u[1] = apu[1]; ap0.u[2] = apu[2]; ap0.u[3] = apu[3];
    ap1.u[0] = apu[4]; ap1.u[1] = apu[5]; ap1.u[2] = apu[6]; ap1.u[3] = apu[7];
    bv.d[0] = x0;  bv.d[1] = x1;
    oacc[0] = __builtin_amdgcn_mfma_f32_16x16x32_bf16(ap0.s, bv.s, oacc[0], 0, 0, 0);
    bv.d[0] = x2;  bv.d[1] = x3;
    oacc[1] = __builtin_amdgcn_mfma_f32_16x16x32_bf16(ap0.s, bv.s, oacc[1], 0, 0, 0);
    bv.d[0] = x4;  bv.d[1] = x5;
    oacc[2] = __builtin_amdgcn_mfma_f32_16x16x32_bf16(ap0.s, bv.s, oacc[2], 0, 0, 0);
    bv.d[0] = x6;  bv.d[1] = x7;
    oacc[3] = __builtin_amdgcn_mfma_f32_16x16x32_bf16(ap0.s, bv.s, oacc[3], 0, 0, 0);
    bv.d[0] = x8;  bv.d[1] = x9;
    oacc[0] = __builtin_amdgcn_mfma_f32_16x16x32_bf16(ap1.s, bv.s, oacc[0], 0, 0, 0);
    bv.d[0] = x10; bv.d[1] = x11;
    oacc[1] = __builtin_amdgcn_mfma_f32_16x16x32_bf16(ap1.s, bv.s, oacc[1], 0, 0, 0);
    bv.d[0] = x12; bv.d[1] = x13;
    oacc[2] = __builtin_amdgcn_mfma_f32_16x16x32_bf16(ap1.s, bv.s, oacc[2], 0, 0, 0);
    bv.d[0] = x14; bv.d[1] = x15;
    oacc[3] = __builtin_amdgcn_mfma_f32_16x16x32_bf16(ap1.s, bv.s, oacc[3], 0, 0, 0);
    mw = mwn;
  }

  // epilogue: O store (C rows = query offset quad*4+r, cols = d = c*16+ln15)
#pragma unroll
  for (int c = 0; c < 4; ++c) {
#pragma unroll
    for (int r = 0; r < 4; ++r) {
      Og[qkvbase + (size_t)(q0 + w * 16 + quad * 4 + r) * D + c * 16 + ln15] = oacc[c][r];
    }
  }
}

extern "C" void kernel_launch(void* const* d_in, const int* in_sizes, int n_in,
                              void* d_out, int out_size, void* d_ws, size_t ws_size,
                              hipStream_t stream) {
  const float* q = (const float*)d_in[0];
  const float* k = (const float*)d_in[1];
  const float* v = (const float*)d_in[2];
  const int* m = (const int*)d_in[3];
  float* outp = (float*)d_out;
  float* attnp = outp + (size_t)BB * HH * S * D;
  unsigned long long* bits = (unsigned long long*)d_ws;  // 1 MB

  const int nwords = BB * S * (S / 64);  // 131072
  pack_mask_kernel<<<nwords / 4, 256, 0, stream>>>(m, bits);
  dim3 grid(BB * HH, S / 64);
  attn_kernel<<<grid, 256, 0, stream>>>(q, k, v, bits, outp, attnp);
}